// Round 1
// baseline (182.585 us; speedup 1.0000x reference)
//
#include <hip/hip_runtime.h>
#include <hip/hip_bf16.h>
#include <math.h>

// Problem constants (fixed by setup_inputs)
#define M_TOT 2
#define N_TOT 4096
#define DZ    64
#define G_TOT 16384

// Tiling: 512-thread blocks (8 waves), each wave owns 32 g-rows (two A-frags).
// Grid = (G/BG=64, m=2, NSPLIT=8) = 1024 blocks = 4 blocks/CU = 32 waves/CU
// (was 16 waves/CU at 256T/NSPLIT=4 -> occupancy was the bottleneck: 32.6%
// measured, no pipe saturated: VALU 52%, MFMA 11%, HBM 10%).
#define BG      256
#define BN      64
#define THREADS 512
#define NSPLIT  8
#define NCHUNK  (N_TOT / NSPLIT)   // 512
#define ITERS   (NCHUNK / BN)      // 8
// zT: bf16 [dz=64][n=64], row = 128 B. Full 3-bit XOR swizzle of the 16B block:
// phys_block = logical_block ^ ((row>>1)&7). Conflict-free for the b64 staging
// writes (4 dwords/bank = b64 floor, re-derived for the 512T thread map below)
// and the b128 B-frag reads (8 dwords/bank = b128 floor). k-order inside 16B
// blocks preserved.
#define ZROW_B  128
#define ZT_B    (DZ * ZROW_B)      // 8192
#define KX_OFS  ZT_B               // 8192
#define KY_OFS  (KX_OFS + BN * 4)  // 8448
#define HK_OFS  (KY_OFS + BN * 4)  // 8704
#define BUF_B   (HK_OFS + BN * 4)  // 8960 bytes per pipeline buffer

typedef __attribute__((ext_vector_type(8))) short short8;  // 8 bf16 MFMA A/B frag
typedef __attribute__((ext_vector_type(4))) float f32x4;   // MFMA C/D frag
typedef __attribute__((ext_vector_type(4))) int   int4v;

#if __has_builtin(__builtin_amdgcn_cvt_pk_bf16_f32)
typedef __attribute__((ext_vector_type(2))) __bf16 bf16x2;
__device__ __forceinline__ unsigned int pack_bf16_pair(float lo, float hi) {
    return __builtin_bit_cast(unsigned int, __builtin_amdgcn_cvt_pk_bf16_f32(lo, hi));
}
#else
__device__ __forceinline__ unsigned int pack_bf16_pair(float lo, float hi) {
    const unsigned int a = __float_as_uint(lo) + 0x8000u;  // round-half-up to bf16
    const unsigned int b = __float_as_uint(hi) + 0x8000u;
    return __builtin_amdgcn_perm(b, a, 0x07060302u);       // [lo[31:16], hi[31:16]]
}
#endif

__global__ __launch_bounds__(THREADS, 8)  // 8 waves/EU -> 4 blocks/CU co-resident
void setconv_kernel(const float* __restrict__ x,       // [2][4096][2]
                    const float* __restrict__ z,       // [2][4096][64]
                    const float* __restrict__ x_grid,  // [2][16384][2]
                    const float* __restrict__ z_grid,  // [2][16384][64]
                    const float* __restrict__ lsp,     // [2]
                    float* __restrict__ out)           // [2][16384][64], memset to 0
{
    __shared__ __align__(16) unsigned char lds[2 * BUF_B];

    const int tid  = threadIdx.x;
    const int wave = tid >> 6;
    const int lane = tid & 63;
    const int quad = lane >> 4;
    const int l16  = lane & 15;

    const int mb    = blockIdx.y;
    const int gbase = blockIdx.x * BG;
    const int nbase = blockIdx.z * NCHUNK;

    const float LOG2E = 1.44269504088896340736f;
    const float inv0 = 1.0f / (1e-5f + log1pf(__expf(lsp[0])));
    const float inv1 = 1.0f / (1e-5f + log1pf(__expf(lsp[1])));

    // Two row-groups per wave: rows wave*32 + {l16, 16+l16}.
    float qxL[2], qyL[2], hq[2];
#pragma unroll
    for (int g = 0; g < 2; g++) {
        const int grow = gbase + wave * 32 + g * 16 + l16;
        const float2 qraw = *(const float2*)&x_grid[(size_t)(mb * G_TOT + grow) * 2];
        const float qx = qraw.x * inv0, qy = qraw.y * inv1;
        qxL[g] = LOG2E * qx;
        qyL[g] = LOG2E * qy;
        hq[g]  = -0.5f * LOG2E * (qx * qx + qy * qy);
    }

    // Staging thread map for 512 threads (tile = 64n x 64dz f32 -> bf16 zT):
    //   sa  = tid & 31  -> dz rows {2sa, 2sa+1}  (consecutive lanes -> consecutive
    //                      dz float2 -> 256B coalesced global loads per n-row)
    //   snq = tid >> 5  -> n-quad, n = snq*4 + j, j=0..3
    // Each thread: 4x float2 loads, packs into two uint2 (8B) LDS writes, one per
    // dz row. Swizzle: logical 16B block = snq>>1, sub-offset = (snq&1)*8,
    // phys = (snq>>1) ^ ((d>>1)&7); d=2sa,2sa+1 share (d>>1)&7 = sa&7.
    // Bank check per b64 write: bank = 4*((w ^ (sa&7))&7) + 2h + {0,1} with
    // w = wave, h = (lane>>5): every bank receives exactly 4 dwords = b64 floor.
    const int sa  = tid & 31;
    const int snq = tid >> 5;
    const float* zb = z + (size_t)mb * N_TOT * DZ + sa * 2;
    const unsigned wblk  = (unsigned)(((snq >> 1) ^ (sa & 7)) & 7) * 16
                         + (unsigned)(snq & 1) * 8;
    const unsigned wrow0 = (unsigned)(sa * 2) * ZROW_B + wblk;   // dz row 2sa
    // dz row 2sa+1 = wrow0 + ZROW_B (same banks, separate instruction)

    // Swizzled read bases: row r = nt*16 + l16 -> swz = (l16>>1)&7 (nt*8 ≡ 0 mod 8);
    // block b = kc*4 + quad -> phys = (quad ^ swz) ^ (kc*4).
    const unsigned swz_l = (unsigned)((l16 >> 1) & 7);
    const unsigned q0    = (unsigned)quad ^ swz_l;
    const unsigned rbA   = (unsigned)l16 * ZROW_B + q0 * 16;         // kc = 0
    const unsigned rbB   = (unsigned)l16 * ZROW_B + (q0 ^ 4u) * 16;  // kc = 1

    f32x4 acc[2][4];
#pragma unroll
    for (int g = 0; g < 2; g++)
#pragma unroll
        for (int i = 0; i < 4; i++) acc[g][i] = (f32x4){0.f, 0.f, 0.f, 0.f};

    auto stage = [&](unsigned dst, const float2* zf, float2 kraw) {
        uint2 lo, hi;
        lo.x = pack_bf16_pair(zf[0].x, zf[1].x);   // zT[2sa][n..n+1]
        lo.y = pack_bf16_pair(zf[2].x, zf[3].x);   // zT[2sa][n+2..n+3]
        hi.x = pack_bf16_pair(zf[0].y, zf[1].y);   // zT[2sa+1][n..n+1]
        hi.y = pack_bf16_pair(zf[2].y, zf[3].y);   // zT[2sa+1][n+2..n+3]
        *(uint2*)(lds + dst + wrow0)          = lo;
        *(uint2*)(lds + dst + wrow0 + ZROW_B) = hi;
        if (tid < BN) {
            const float kx = kraw.x * inv0, ky = kraw.y * inv1;
            *(float*)(lds + dst + KX_OFS + tid * 4) = kx;
            *(float*)(lds + dst + KY_OFS + tid * 4) = ky;
            *(float*)(lds + dst + HK_OFS + tid * 4) = -0.5f * LOG2E * (kx * kx + ky * ky);
        }
    };

    // ---- prologue: fetch + stage tile 0 into buffer 0 ----
    {
        float2 zf[4];
        float2 kraw = {0.f, 0.f};
        const float* zp = zb + (size_t)(nbase + snq * 4) * DZ;
#pragma unroll
        for (int j = 0; j < 4; j++) zf[j] = *(const float2*)(zp + j * DZ);
        if (tid < BN) kraw = *(const float2*)(x + (size_t)(mb * N_TOT + nbase + tid) * 2);
        stage(0u, zf, kraw);
    }
    __syncthreads();

    for (int t = 0; t < ITERS; t++) {
        const unsigned bo = (unsigned)((t & 1) ? BUF_B : 0);
        const unsigned bn = bo ^ (unsigned)BUF_B;

        // ---- issue next tile's global loads (latency hidden under compute) ----
        float2 zf[4];
        float2 kraw = {0.f, 0.f};
        if (t + 1 < ITERS) {
            const int nb1 = nbase + (t + 1) * BN;
            const float* zp = zb + (size_t)(nb1 + snq * 4) * DZ;
#pragma unroll
            for (int j = 0; j < 4; j++) zf[j] = *(const float2*)(zp + j * DZ);
            if (tid < BN) kraw = *(const float2*)(x + (size_t)(mb * N_TOT + nb1 + tid) * 2);
        }

        // ---- compute tile t from buffer bo ----
#pragma unroll
        for (int kc = 0; kc < 2; kc++) {
            const unsigned kb = bo + (unsigned)(kc * 128 + quad * 32);
            const float4 kxa = *(const float4*)(lds + kb + KX_OFS);
            const float4 kxb = *(const float4*)(lds + kb + KX_OFS + 16);
            const float4 kya = *(const float4*)(lds + kb + KY_OFS);
            const float4 kyb = *(const float4*)(lds + kb + KY_OFS + 16);
            const float4 hka = *(const float4*)(lds + kb + HK_OFS);
            const float4 hkb = *(const float4*)(lds + kb + HK_OFS + 16);
            const float kxr[8] = {kxa.x, kxa.y, kxa.z, kxa.w, kxb.x, kxb.y, kxb.z, kxb.w};
            const float kyr[8] = {kya.x, kya.y, kya.z, kya.w, kyb.x, kyb.y, kyb.z, kyb.w};
            const float hkr[8] = {hka.x, hka.y, hka.z, hka.w, hkb.x, hkb.y, hkb.z, hkb.w};

            // Weights for both row-groups, directly in A-frag layout.
            unsigned aw[2][4];
#pragma unroll
            for (int jp = 0; jp < 4; jp++) {
#pragma unroll
                for (int g = 0; g < 2; g++) {
                    const float s0 = fmaf(qxL[g], kxr[2 * jp],
                                      fmaf(qyL[g], kyr[2 * jp], hq[g] + hkr[2 * jp]));
                    const float s1 = fmaf(qxL[g], kxr[2 * jp + 1],
                                      fmaf(qyL[g], kyr[2 * jp + 1], hq[g] + hkr[2 * jp + 1]));
                    aw[g][jp] = pack_bf16_pair(__builtin_amdgcn_exp2f(s0),
                                               __builtin_amdgcn_exp2f(s1));
                }
            }
            const int4v  a0v = {(int)aw[0][0], (int)aw[0][1], (int)aw[0][2], (int)aw[0][3]};
            const int4v  a1v = {(int)aw[1][0], (int)aw[1][1], (int)aw[1][2], (int)aw[1][3]};
            const short8 af0 = __builtin_bit_cast(short8, a0v);
            const short8 af1 = __builtin_bit_cast(short8, a1v);

            // B-frags (shared by both row-groups) + 8 MFMA.
            const unsigned rb = bo + ((kc == 0) ? rbA : rbB);
#pragma unroll
            for (int nt = 0; nt < 4; nt++) {
                const short8 bfrag = *(const short8*)(lds + rb + nt * (16 * ZROW_B));
                acc[0][nt] = __builtin_amdgcn_mfma_f32_16x16x32_bf16(af0, bfrag, acc[0][nt], 0, 0, 0);
                acc[1][nt] = __builtin_amdgcn_mfma_f32_16x16x32_bf16(af1, bfrag, acc[1][nt], 0, 0, 0);
            }
        }

        // ---- stage next tile into buffer bn; single barrier per iteration ----
        if (t + 1 < ITERS) {
            stage(bn, zf, kraw);
            __syncthreads();
        }
    }

    // ---- epilogue: C/D layout col = lane&15 (dz), row = quad*4 + reg (g-row) ----
    // out was memset to 0; all 8 n-splits atomicAdd. Split 0 folds z_grid in.
    const bool add_zg = (blockIdx.z == 0);
#pragma unroll
    for (int g = 0; g < 2; g++) {
        const int gout = gbase + wave * 32 + g * 16 + quad * 4;
#pragma unroll
        for (int nt = 0; nt < 4; nt++) {
#pragma unroll
            for (int r = 0; r < 4; r++) {
                const size_t idx = (size_t)(mb * G_TOT + gout + r) * DZ + nt * 16 + l16;
                const float v = add_zg ? (acc[g][nt][r] + z_grid[idx]) : acc[g][nt][r];
                atomicAdd(&out[idx], v);
            }
        }
    }
}

extern "C" void kernel_launch(void* const* d_in, const int* in_sizes, int n_in,
                              void* d_out, int out_size, void* d_ws, size_t ws_size,
                              hipStream_t stream) {
    const float* x   = (const float*)d_in[0];
    const float* z   = (const float*)d_in[1];
    const float* xg  = (const float*)d_in[2];
    const float* zgr = (const float*)d_in[3];
    const float* lsp = (const float*)d_in[4];
    float* out = (float*)d_out;

    // out = 0 (write-only memset node; z_grid folded in by split 0's atomics)
    hipMemsetAsync(out, 0, sizeof(float) * (size_t)M_TOT * G_TOT * DZ, stream);

    dim3 grid(G_TOT / BG, M_TOT, NSPLIT);
    setconv_kernel<<<grid, THREADS, 0, stream>>>(x, z, xg, zgr, lsp, out);
}